// Round 12
// baseline (183.625 us; speedup 1.0000x reference)
//
#include <hip/hip_runtime.h>
#include <stdint.h>

// CriticNetwork (R12): compute kernel (critic_one minus broadcast) + EXACT
// R4-style broadcast kernel (8192 blocks, RMW from each plane's m=0 row).
// R11 ledger: >=20us fixed gap per iteration; R4 accounting => critic_c ~22us
// (32 blocks/CU of pure-store waves) while every fused broadcast ran ~60us.
//   value[b,i,m] = ve[i] + (sv[i] + w[i,m]*dv[m])/64
//   weights5[b,i,m,j] = w[b,i,j]
// w = sigmoid(K Q^T / sqrt(128)); K/Q = oa @ Wk^T/Wq^T (bf16 MFMA, K-dim
// padded 144->160); u = Wv^T wf2; g = Wenc^T wf1.

#define BB 128
#define NN 64
#define OBSD 128
#define ACTD 16
#define DD 144
#define DKD 128
#define RS 168    // bf16 row stride for s_oa / s_W
#define RSQ 136   // bf16 row stride for s_Q / s_K

typedef float f32x4 __attribute__((ext_vector_type(4)));
typedef short bf16x8 __attribute__((ext_vector_type(8)));

__device__ __forceinline__ unsigned short bf1(float x) {
  unsigned u = __float_as_uint(x);
  return (unsigned short)((u + 0x7fffu + ((u >> 16) & 1u)) >> 16);
}
__device__ __forceinline__ unsigned int pack_bf2(float x, float y) {
  return (unsigned)bf1(x) | ((unsigned)bf1(y) << 16);
}
__device__ __forceinline__ float bf2f(unsigned short s) {
  return __uint_as_float(((unsigned)s) << 16);
}

// grid 512: b = bid>>2, i0 = (bid&3)*16. 512 threads (8 waves).
__global__ __launch_bounds__(512, 1) void critic_one(
    const float* __restrict__ obs, const float* __restrict__ pol,
    const float* __restrict__ act,
    const float* __restrict__ Wk, const float* __restrict__ Wq,
    const float* __restrict__ Wv, const float* __restrict__ Wenc,
    const float* __restrict__ Wfin, float* __restrict__ out)
{
  __shared__ __align__(16) unsigned short s_oa[NN * RS];    // 21504 B
  __shared__ __align__(16) unsigned short s_W[DKD * RS];    // 43008 B (Wq, then Wk)
  __shared__ __align__(16) unsigned short s_Q[NN * RSQ];    // 17408 B
  __shared__ __align__(16) unsigned short s_K[16 * RSQ];    // 4352 B
  __shared__ __align__(16) float s_w[16 * 68];              // 4352 B
  __shared__ unsigned short s_dpa[NN * ACTD];               // 2048 B
  __shared__ float s_u[DD];
  __shared__ float s_g[OBSD];
  __shared__ float s_vas[NN], s_dv[NN], s_ve[16], s_sv[16];

  const int tid = threadIdx.x;
  const int b = blockIdx.x >> 2;
  const int i0 = (blockIdx.x & 3) * 16;
  const int wv = tid >> 6, lane = tid & 63;
  const int m = lane & 15, q = lane >> 4;

  // ================= P0: stage oa, dpa, Wq; compute u,g =================
  {
    const float4* obs4 = (const float4*)(obs + (size_t)b * NN * OBSD);
    for (int idx = tid; idx < 2048; idx += 512) {           // 64 rows x 32 f4
      float4 v = obs4[idx];
      int row = idx >> 5, c4 = (idx & 31) * 4;
      *(uint2*)&s_oa[row * RS + c4] = make_uint2(pack_bf2(v.x, v.y), pack_bf2(v.z, v.w));
    }
    if (tid < 256) {                                        // act/pol: 64 rows x 4 f4
      const float4* act4 = (const float4*)(act + (size_t)b * NN * ACTD);
      const float4* pol4 = (const float4*)(pol + (size_t)b * NN * ACTD);
      float4 a = act4[tid], pp = pol4[tid];
      int row = tid >> 2, t0 = (tid & 3) * 4;
      *(uint2*)&s_oa[row * RS + OBSD + t0] = make_uint2(pack_bf2(a.x, a.y), pack_bf2(a.z, a.w));
      *(uint2*)&s_dpa[row * ACTD + t0] =
          make_uint2(pack_bf2(pp.x - a.x, pp.y - a.y), pack_bf2(pp.z - a.z, pp.w - a.w));
    } else if (tid < 512) {                                 // zero-pad oa cols 144..159
      int idx = tid - 256;
      int row = idx >> 2, c4 = DD + (idx & 3) * 4;
      *(uint2*)&s_oa[row * RS + c4] = make_uint2(0u, 0u);
    }
    const float4* W4 = (const float4*)Wq;                   // 128 rows x 36 f4
    for (int idx = tid; idx < 4608; idx += 512) {
      int row = idx / 36, g4 = idx - row * 36;
      float4 v = W4[idx];
      *(uint2*)&s_W[row * RS + g4 * 4] = make_uint2(pack_bf2(v.x, v.y), pack_bf2(v.z, v.w));
    }
    for (int idx = tid; idx < 512; idx += 512) {            // zero-pad W cols 144..159
      int row = idx >> 2, c4 = DD + (idx & 3) * 4;
      *(uint2*)&s_W[row * RS + c4] = make_uint2(0u, 0u);
    }
    if (tid < DD) {                                         // u[t]
      float a0=0.f,a1=0.f,a2=0.f,a3=0.f,a4=0.f,a5=0.f,a6=0.f,a7=0.f;
      for (int c = 0; c < DKD; c += 8) {
        a0 += Wv[(c+0)*DD + tid] * Wfin[OBSD + c + 0];
        a1 += Wv[(c+1)*DD + tid] * Wfin[OBSD + c + 1];
        a2 += Wv[(c+2)*DD + tid] * Wfin[OBSD + c + 2];
        a3 += Wv[(c+3)*DD + tid] * Wfin[OBSD + c + 3];
        a4 += Wv[(c+4)*DD + tid] * Wfin[OBSD + c + 4];
        a5 += Wv[(c+5)*DD + tid] * Wfin[OBSD + c + 5];
        a6 += Wv[(c+6)*DD + tid] * Wfin[OBSD + c + 6];
        a7 += Wv[(c+7)*DD + tid] * Wfin[OBSD + c + 7];
      }
      s_u[tid] = ((a0+a1)+(a2+a3)) + ((a4+a5)+(a6+a7));
    } else if (tid < DD + OBSD) {                           // g[d]
      const int d = tid - DD;
      float a0=0.f,a1=0.f,a2=0.f,a3=0.f,a4=0.f,a5=0.f,a6=0.f,a7=0.f;
      for (int c = 0; c < 128; c += 8) {
        a0 += Wenc[(c+0)*OBSD + d] * Wfin[c + 0];
        a1 += Wenc[(c+1)*OBSD + d] * Wfin[c + 1];
        a2 += Wenc[(c+2)*OBSD + d] * Wfin[c + 2];
        a3 += Wenc[(c+3)*OBSD + d] * Wfin[c + 3];
        a4 += Wenc[(c+4)*OBSD + d] * Wfin[c + 4];
        a5 += Wenc[(c+5)*OBSD + d] * Wfin[c + 5];
        a6 += Wenc[(c+6)*OBSD + d] * Wfin[c + 6];
        a7 += Wenc[(c+7)*OBSD + d] * Wfin[c + 7];
      }
      s_g[d] = ((a0+a1)+(a2+a3)) + ((a4+a5)+(a6+a7));
    }
  }
  __syncthreads();

  // ====== P1: Q = oa @ Wq^T (full 64 rows). wave: jt = wv&3, ntiles (wv>>2)*4..+3
  {
    const int jt = wv & 3, n0 = (wv >> 2) * 4;
    f32x4 acc[4];
    #pragma unroll
    for (int t = 0; t < 4; ++t) acc[t] = (f32x4){0.f, 0.f, 0.f, 0.f};
    #pragma unroll
    for (int ks = 0; ks < 5; ++ks) {
      const int koff = ks * 32 + q * 8;
      bf16x8 a = *(const bf16x8*)&s_oa[(jt * 16 + m) * RS + koff];
      #pragma unroll
      for (int t = 0; t < 4; ++t) {
        bf16x8 bb = *(const bf16x8*)&s_W[((n0 + t) * 16 + m) * RS + koff];
        acc[t] = __builtin_amdgcn_mfma_f32_16x16x32_bf16(a, bb, acc[t], 0, 0, 0);
      }
    }
    #pragma unroll
    for (int t = 0; t < 4; ++t)
      #pragma unroll
      for (int r = 0; r < 4; ++r)
        s_Q[(jt * 16 + q * 4 + r) * RSQ + (n0 + t) * 16 + m] = bf1(acc[t][r]);
  }
  __syncthreads();                       // Wq reads done -> safe to overwrite s_W

  // ====== P2: re-stage s_W <- Wk
  {
    const float4* W4 = (const float4*)Wk;
    for (int idx = tid; idx < 4608; idx += 512) {
      int row = idx / 36, g4 = idx - row * 36;
      float4 v = W4[idx];
      *(uint2*)&s_W[row * RS + g4 * 4] = make_uint2(pack_bf2(v.x, v.y), pack_bf2(v.z, v.w));
    }
  }
  __syncthreads();

  // ====== P3: K16 = oa[i0..i0+15] @ Wk^T. wave wv -> ntile wv
  {
    f32x4 acc = (f32x4){0.f, 0.f, 0.f, 0.f};
    #pragma unroll
    for (int ks = 0; ks < 5; ++ks) {
      const int koff = ks * 32 + q * 8;
      bf16x8 a = *(const bf16x8*)&s_oa[(i0 + m) * RS + koff];
      bf16x8 bb = *(const bf16x8*)&s_W[(wv * 16 + m) * RS + koff];
      acc = __builtin_amdgcn_mfma_f32_16x16x32_bf16(a, bb, acc, 0, 0, 0);
    }
    #pragma unroll
    for (int r = 0; r < 4; ++r)
      s_K[(q * 4 + r) * RSQ + wv * 16 + m] = bf1(acc[r]);
  }
  __syncthreads();

  // ====== P4: scores (waves 0-3) || vas/dv/ve (waves 4-6)
  if (wv < 4) {
    f32x4 sc = (f32x4){0.f, 0.f, 0.f, 0.f};
    #pragma unroll
    for (int ks = 0; ks < 4; ++ks) {
      const int koff = ks * 32 + q * 8;
      bf16x8 a = *(const bf16x8*)&s_K[m * RSQ + koff];
      bf16x8 bb = *(const bf16x8*)&s_Q[(wv * 16 + m) * RSQ + koff];
      sc = __builtin_amdgcn_mfma_f32_16x16x32_bf16(a, bb, sc, 0, 0, 0);
    }
    const float kk = 0.08838834764831845f;   // 1/sqrt(128)
    #pragma unroll
    for (int r = 0; r < 4; ++r)
      s_w[(q * 4 + r) * 68 + wv * 16 + m] = 1.0f / (1.0f + __expf(-sc[r] * kk));
  } else if (wv == 4) {
    float a = 0.f;
    #pragma unroll
    for (int t = 0; t < ACTD; ++t) a += bf2f(s_dpa[lane * ACTD + t]) * s_u[OBSD + t];
    s_dv[lane] = a;
  } else if (wv == 5) {
    float a = 0.f;
    for (int d = 0; d < DD; ++d) a += bf2f(s_oa[lane * RS + d]) * s_u[d];
    s_vas[lane] = a;
  } else if (wv == 6 && lane < 16) {
    float a = 0.f;
    for (int d = 0; d < OBSD; ++d) a += bf2f(s_oa[(i0 + lane) * RS + d]) * s_g[d];
    s_ve[lane] = a;
  }
  __syncthreads();

  if (tid < 16) {
    float a = 0.f;
    for (int j = 0; j < NN; ++j) a += s_w[tid * 68 + j] * s_vas[j];
    s_sv[tid] = a;
  }
  __syncthreads();

  // ====== P5: value rows + w rows into each plane's m=0 row
  if (tid < 256) {
    const int r = tid >> 4, m4 = (tid & 15) * 4;
    float4 v;
    v.x = s_ve[r] + (s_sv[r] + s_w[r * 68 + m4 + 0] * s_dv[m4 + 0]) * (1.0f / 64.0f);
    v.y = s_ve[r] + (s_sv[r] + s_w[r * 68 + m4 + 1] * s_dv[m4 + 1]) * (1.0f / 64.0f);
    v.z = s_ve[r] + (s_sv[r] + s_w[r * 68 + m4 + 2] * s_dv[m4 + 2]) * (1.0f / 64.0f);
    v.w = s_ve[r] + (s_sv[r] + s_w[r * 68 + m4 + 3] * s_dv[m4 + 3]) * (1.0f / 64.0f);
    *(float4*)(out + ((size_t)(b * 64 + i0 + r) * 64 + m4)) = v;
  } else {
    const int x = tid - 256;                 // 256 = 16 rows x 16 f4
    const int r = x >> 4, j4 = x & 15;
    float* w5 = out + (size_t)BB * NN * NN;
    *(float4*)(w5 + ((size_t)(b * 64 + i0 + r) << 12) + j4 * 4) =
        *(const float4*)&s_w[r * 68 + j4 * 4];
  }
}

// EXACT R4-shape broadcast: one block per plane (8192 blocks), read the m=0
// row (written by critic_one), replicate to all 64 m-rows. Benign same-value
// race on row 0. ~32 blocks/CU of pure-store waves.
__global__ __launch_bounds__(256, 4) void critic_c(float* __restrict__ out) {
  float4* dst = (float4*)(out + (size_t)BB * NN * NN + (size_t)blockIdx.x * NN * NN);
  const int j4 = threadIdx.x & 15;           // 16 float4 per j-row
  const int m0 = threadIdx.x >> 4;           // 0..15
  const float4 v = dst[j4];
  dst[(size_t)(m0 +  0) * 16 + j4] = v;
  dst[(size_t)(m0 + 16) * 16 + j4] = v;
  dst[(size_t)(m0 + 32) * 16 + j4] = v;
  dst[(size_t)(m0 + 48) * 16 + j4] = v;
}

extern "C" void kernel_launch(void* const* d_in, const int* in_sizes, int n_in,
                              void* d_out, int out_size, void* d_ws, size_t ws_size,
                              hipStream_t stream) {
  (void)in_sizes; (void)n_in; (void)out_size; (void)d_ws; (void)ws_size;
  const float* obs  = (const float*)d_in[0];
  const float* pol  = (const float*)d_in[1];
  const float* act  = (const float*)d_in[2];
  const float* Wk   = (const float*)d_in[3];
  const float* Wq   = (const float*)d_in[4];
  const float* Wv   = (const float*)d_in[5];
  const float* Wenc = (const float*)d_in[6];
  const float* Wfin = (const float*)d_in[7];
  float* out = (float*)d_out;
  hipLaunchKernelGGL(critic_one, dim3(BB * 4), dim3(512), 0, stream,
                     obs, pol, act, Wk, Wq, Wv, Wenc, Wfin, out);
  hipLaunchKernelGGL(critic_c, dim3(BB * NN), dim3(256), 0, stream, out);
}

// Round 13
// 166.397 us; speedup vs baseline: 1.1035x; 1.1035x over previous
//
#include <hip/hip_runtime.h>
#include <stdint.h>

// CriticNetwork (R13 = R10 structure + LDS diet for occupancy):
//   value[b,i,m] = ve[i] + (sv[i] + w[i,m]*dv[m])/64
//   weights5[b,i,m,j] = w[b,i,j]
// scores = oa (Wk^T Wq) oa^T via MT trick. setup: MT bf16 + u + g -> ws.
// fused: T = oa16 x MT^T with B-fragments loaded DIRECT FROM GLOBAL (L2-hit,
// no 48KB LDS stage) -> LDS ~35KB -> 4 blk/CU (R10 had 2, R11/R12 had 1).
// R12 ledger: broadcast-in vs broadcast-out identical => stores never the
// bottleneck; occupancy during barrier-chained phases is. 

#define BB 128
#define NN 64
#define OBSD 128
#define ACTD 16
#define DD 144
#define DKD 128
#define RS 168   // LDS bf16 row stride (s_oa, s_T)

typedef float f32x4 __attribute__((ext_vector_type(4)));
typedef short bf16x8 __attribute__((ext_vector_type(8)));

// ws: ushort MT[144*160] (row-major [e][d], d zero-padded to 160) at 0;
// float u[144] at F_U; float g[128] at F_G.
#define F_U 16384
#define F_G (F_U + 256)

__device__ __forceinline__ unsigned short bf1(float x) {
  unsigned u = __float_as_uint(x);
  return (unsigned short)((u + 0x7fffu + ((u >> 16) & 1u)) >> 16);
}
__device__ __forceinline__ unsigned int pack_bf2(float x, float y) {
  return (unsigned)bf1(x) | ((unsigned)bf1(y) << 16);
}
__device__ __forceinline__ float bf2f(unsigned short s) {
  return __uint_as_float(((unsigned)s) << 16);
}

// ---------------- setup: MT (144 rows) + u + g ----------------
__global__ __launch_bounds__(256) void critic_setup(
    const float* __restrict__ Wk, const float* __restrict__ Wq,
    const float* __restrict__ Wv, const float* __restrict__ Wenc,
    const float* __restrict__ Wfin, float* __restrict__ ws)
{
  const int bid = blockIdx.x, t = threadIdx.x;
  if (bid < DD) {                       // MT[e][d] = sum_c Wk[c,d] Wq[c,e]
    const int e = bid;
    if (t < 160) {
      float acc = 0.f;
      if (t < DD) {
        float a0=0.f,a1=0.f,a2=0.f,a3=0.f;
        for (int c = 0; c < DKD; c += 4) {
          a0 += Wk[(c+0)*DD + t] * Wq[(c+0)*DD + e];
          a1 += Wk[(c+1)*DD + t] * Wq[(c+1)*DD + e];
          a2 += Wk[(c+2)*DD + t] * Wq[(c+2)*DD + e];
          a3 += Wk[(c+3)*DD + t] * Wq[(c+3)*DD + e];
        }
        acc = (a0+a1)+(a2+a3);
      }
      ((unsigned short*)ws)[e * 160 + t] = bf1(acc);
    }
  } else if (bid == DD) {               // u[t] = sum_c Wv[c,t] Wfin[128+c]
    if (t < DD) {
      float a0=0.f,a1=0.f,a2=0.f,a3=0.f;
      for (int c = 0; c < DKD; c += 4) {
        a0 += Wv[(c+0)*DD + t] * Wfin[OBSD + c + 0];
        a1 += Wv[(c+1)*DD + t] * Wfin[OBSD + c + 1];
        a2 += Wv[(c+2)*DD + t] * Wfin[OBSD + c + 2];
        a3 += Wv[(c+3)*DD + t] * Wfin[OBSD + c + 3];
      }
      ws[F_U + t] = (a0+a1)+(a2+a3);
    }
  } else {                              // g[d] = sum_c Wenc[c,d] Wfin[c]
    if (t < OBSD) {
      float a0=0.f,a1=0.f,a2=0.f,a3=0.f;
      for (int c = 0; c < 128; c += 4) {
        a0 += Wenc[(c+0)*OBSD + t] * Wfin[c + 0];
        a1 += Wenc[(c+1)*OBSD + t] * Wfin[c + 1];
        a2 += Wenc[(c+2)*OBSD + t] * Wfin[c + 2];
        a3 += Wenc[(c+3)*OBSD + t] * Wfin[c + 3];
      }
      ws[F_G + t] = (a0+a1)+(a2+a3);
    }
  }
}

// ---------------- fused: grid 512 (b = bid>>2, i0 = (bid&3)*16), 512 thr ----
// LDS ~35 KB -> 4 blocks/CU.
__global__ __launch_bounds__(512, 2) void critic_fused(
    const float* __restrict__ obs, const float* __restrict__ pol,
    const float* __restrict__ act, const float* __restrict__ ws,
    float* __restrict__ out)
{
  __shared__ __align__(16) unsigned short s_oa[NN * RS];    // 21504 B
  __shared__ __align__(16) unsigned short s_T[16 * RS];     // 5376 B
  __shared__ __align__(16) float s_w[16 * 68];              // 4352 B
  __shared__ unsigned short s_dpa[NN * ACTD];               // 2048 B
  __shared__ float s_u[DD];
  __shared__ float s_g[OBSD];
  __shared__ float s_vas[NN], s_dv[NN], s_ve[16], s_sv[16];

  const int tid = threadIdx.x;
  const int b = blockIdx.x >> 2;
  const int i0 = (blockIdx.x & 3) * 16;
  const int wv = tid >> 6, lane = tid & 63;
  const int m = lane & 15, q = lane >> 4;
  const unsigned short* mt = (const unsigned short*)ws;

  // ---- P0: stage oa (bf16) + dpa; u,g from ws
  {
    const float4* obs4 = (const float4*)(obs + (size_t)b * NN * OBSD);
    for (int idx = tid; idx < 2048; idx += 512) {   // 64 rows x 32 f4
      float4 v = obs4[idx];
      int row = idx >> 5, c4 = (idx & 31) * 4;
      *(uint2*)&s_oa[row * RS + c4] = make_uint2(pack_bf2(v.x, v.y), pack_bf2(v.z, v.w));
    }
    if (tid < 256) {                                // act/pol: 64 rows x 4 f4
      const float4* act4 = (const float4*)(act + (size_t)b * NN * ACTD);
      const float4* pol4 = (const float4*)(pol + (size_t)b * NN * ACTD);
      float4 a = act4[tid], pp = pol4[tid];
      int row = tid >> 2, t0 = (tid & 3) * 4;
      *(uint2*)&s_oa[row * RS + OBSD + t0] = make_uint2(pack_bf2(a.x, a.y), pack_bf2(a.z, a.w));
      *(uint2*)&s_dpa[row * ACTD + t0] =
          make_uint2(pack_bf2(pp.x - a.x, pp.y - a.y), pack_bf2(pp.z - a.z, pp.w - a.w));
    } else if (tid < 512) {                         // zero-pad oa cols 144..159
      int idx = tid - 256;
      int row = idx >> 2, c4 = DD + (idx & 3) * 4;
      *(uint2*)&s_oa[row * RS + c4] = make_uint2(0u, 0u);
    }
    if (tid < DD)             s_u[tid] = ws[F_U + tid];
    else if (tid < DD + OBSD) s_g[tid - DD] = ws[F_G + (tid - DD)];
  }
  __syncthreads();

  // ---- P1: T = oa[i0..+15] x MT^T. B-fragments DIRECT from global (L2-hit).
  // wave wv -> e-tile wv; wave 0 also e-tile 8.
  f32x4 accT = (f32x4){0.f, 0.f, 0.f, 0.f};
  f32x4 accT8 = (f32x4){0.f, 0.f, 0.f, 0.f};
  #pragma unroll
  for (int ks = 0; ks < 5; ++ks) {
    const int koff = ks * 32 + q * 8;
    bf16x8 a = *(const bf16x8*)&s_oa[(i0 + m) * RS + koff];
    bf16x8 bb = *(const bf16x8*)&mt[(wv * 16 + m) * 160 + koff];
    accT = __builtin_amdgcn_mfma_f32_16x16x32_bf16(a, bb, accT, 0, 0, 0);
    if (wv == 0) {
      bf16x8 b8 = *(const bf16x8*)&mt[(128 + m) * 160 + koff];
      accT8 = __builtin_amdgcn_mfma_f32_16x16x32_bf16(a, b8, accT8, 0, 0, 0);
    }
  }
  // write T (bf16) + zero-pad cols 144..159
  #pragma unroll
  for (int r = 0; r < 4; ++r)
    s_T[(q * 4 + r) * RS + wv * 16 + m] = bf1(accT[r]);
  if (wv == 0)
    #pragma unroll
    for (int r = 0; r < 4; ++r)
      s_T[(q * 4 + r) * RS + 128 + m] = bf1(accT8[r]);
  if (tid < 32) {
    int row = tid >> 1, h = tid & 1;
    *(uint4*)&s_T[row * RS + DD + h * 8] = make_uint4(0u, 0u, 0u, 0u);
  }
  __syncthreads();

  // ---- P2: scores (waves 0-3, j-tile = wv) || vas/dv/ve (waves 4-6)
  if (wv < 4) {
    f32x4 sc = (f32x4){0.f, 0.f, 0.f, 0.f};
    #pragma unroll
    for (int ks = 0; ks < 5; ++ks) {
      const int koff = ks * 32 + q * 8;
      bf16x8 a = *(const bf16x8*)&s_T[m * RS + koff];
      bf16x8 bb = *(const bf16x8*)&s_oa[(wv * 16 + m) * RS + koff];
      sc = __builtin_amdgcn_mfma_f32_16x16x32_bf16(a, bb, sc, 0, 0, 0);
    }
    const float kk = 0.08838834764831845f;          // 1/sqrt(128)
    #pragma unroll
    for (int r = 0; r < 4; ++r)
      s_w[(q * 4 + r) * 68 + wv * 16 + m] = 1.0f / (1.0f + __expf(-sc[r] * kk));
  } else if (wv == 4) {                             // dv[m]
    float a = 0.f;
    #pragma unroll
    for (int t = 0; t < ACTD; ++t) a += bf2f(s_dpa[lane * ACTD + t]) * s_u[OBSD + t];
    s_dv[lane] = a;
  } else if (wv == 5) {                             // vas[j]
    float a = 0.f;
    for (int d = 0; d < DD; ++d) a += bf2f(s_oa[lane * RS + d]) * s_u[d];
    s_vas[lane] = a;
  } else if (wv == 6 && lane < 16) {                // ve (this block's rows)
    float a = 0.f;
    for (int d = 0; d < OBSD; ++d) a += bf2f(s_oa[(i0 + lane) * RS + d]) * s_g[d];
    s_ve[lane] = a;
  }
  __syncthreads();

  if (tid < 16) {                                   // sv[i]
    float a = 0.f;
    for (int j = 0; j < NN; ++j) a += s_w[tid * 68 + j] * s_vas[j];
    s_sv[tid] = a;
  }
  __syncthreads();

  // ---- P3: value rows
  if (tid < 256) {
    const int r = tid >> 4, m4 = (tid & 15) * 4;
    float4 v;
    v.x = s_ve[r] + (s_sv[r] + s_w[r * 68 + m4 + 0] * s_dv[m4 + 0]) * (1.0f / 64.0f);
    v.y = s_ve[r] + (s_sv[r] + s_w[r * 68 + m4 + 1] * s_dv[m4 + 1]) * (1.0f / 64.0f);
    v.z = s_ve[r] + (s_sv[r] + s_w[r * 68 + m4 + 2] * s_dv[m4 + 2]) * (1.0f / 64.0f);
    v.w = s_ve[r] + (s_sv[r] + s_w[r * 68 + m4 + 3] * s_dv[m4 + 3]) * (1.0f / 64.0f);
    *(float4*)(out + ((size_t)(b * 64 + i0 + r) * 64 + m4)) = v;
  }

  // ---- P4: broadcast (16 planes x 16 KB), coalesced float4
  float* w5 = out + (size_t)BB * NN * NN;
  #pragma unroll 4
  for (int r = 0; r < 16; ++r) {
    const float4 wv4 = *(const float4*)&s_w[r * 68 + (tid & 15) * 4];
    float4* p4 = (float4*)(w5 + ((size_t)(b * 64 + i0 + r) << 12));
    p4[tid]       = wv4;
    p4[tid + 512] = wv4;
  }
}

extern "C" void kernel_launch(void* const* d_in, const int* in_sizes, int n_in,
                              void* d_out, int out_size, void* d_ws, size_t ws_size,
                              hipStream_t stream) {
  (void)in_sizes; (void)n_in; (void)out_size; (void)ws_size;
  const float* obs  = (const float*)d_in[0];
  const float* pol  = (const float*)d_in[1];
  const float* act  = (const float*)d_in[2];
  const float* Wk   = (const float*)d_in[3];
  const float* Wq   = (const float*)d_in[4];
  const float* Wv   = (const float*)d_in[5];
  const float* Wenc = (const float*)d_in[6];
  const float* Wfin = (const float*)d_in[7];
  float* out = (float*)d_out;
  float* ws  = (float*)d_ws;
  hipLaunchKernelGGL(critic_setup, dim3(DD + 2), dim3(256), 0, stream,
                     Wk, Wq, Wv, Wenc, Wfin, ws);
  hipLaunchKernelGGL(critic_fused, dim3(BB * 4), dim3(512), 0, stream,
                     obs, pol, act, ws, out);
}